// Round 1
// baseline (653.178 us; speedup 1.0000x reference)
//
#include <hip/hip_runtime.h>

#define HS 512
#define WSZ 512
#define NC 64
#define HW (HS * WSZ)

// ---------------------------------------------------------------------------
// Transpose ref (C,H,W) -> refT (H*W, C) so a wave (lane=channel) reads one
// pixel's 64 channels as a contiguous 256B segment.
// Block handles 64 pixels x 64 channels via a padded LDS tile.
// ---------------------------------------------------------------------------
__global__ __launch_bounds__(256) void transpose_kernel(
    const float* __restrict__ ref, float* __restrict__ refT)
{
    __shared__ float lds[64 * 65];   // +1 pad: write stride 65 -> 2-way (free)
    const int p0  = blockIdx.x * 64;
    const int tid = threadIdx.x;
#pragma unroll
    for (int k = 0; k < 16; ++k) {
        int e = k * 256 + tid;
        int c = e >> 6;          // channel
        int i = e & 63;          // pixel within tile
        lds[i * 65 + c] = ref[(size_t)c * HW + p0 + i];   // coalesced read
    }
    __syncthreads();
#pragma unroll
    for (int k = 0; k < 16; ++k) {
        int e = k * 256 + tid;
        int i = e >> 6;
        int c = e & 63;
        refT[(size_t)(p0 + i) * NC + c] = lds[i * 65 + c]; // coalesced write
    }
}

// ---------------------------------------------------------------------------
// Build per-bin linked lists inverting nnf_rs:  bin = nnf_rs[r] (the target
// center this ref pixel scatters to).  head[bin] -> r -> next[r] -> ...
// ---------------------------------------------------------------------------
__global__ __launch_bounds__(256) void fill_kernel(
    const int2* __restrict__ nnf_rs, int* __restrict__ head,
    int* __restrict__ nextp)
{
    int r = blockIdx.x * 256 + threadIdx.x;
    int2 s = nnf_rs[r];               // s.x = sy, s.y = sx  (last-dim order)
    int bin = s.x * WSZ + s.y;        // nnf values guaranteed in [0,512)
    int old = atomicExch(&head[bin], r);
    nextp[r] = old;
}

// ---------------------------------------------------------------------------
// Main gather: one wave per target pixel, lane = channel.
// Pass1: t receives ref[nnf_sr[t-d]+d]*ws for each in-range d.
// Pass2: t receives ref[r+d]*wr for each r with nnf_rs[r]==t-d (via lists).
// TRANSPOSED=false fallback reads channel-major ref directly (ws too small).
// ---------------------------------------------------------------------------
template <bool TRANSPOSED>
__global__ __launch_bounds__(256) void gather_kernel(
    const float* __restrict__ refp,
    const int2* __restrict__ nnf_sr,
    const int*  __restrict__ head,
    const int*  __restrict__ nextp,
    float* __restrict__ out)
{
    const float ws = 1.0f / (float)HW;
    const float wr = 2.0f / (float)HW;

    const int wave = threadIdx.x >> 6;
    const int lane = threadIdx.x & 63;
    const int t    = blockIdx.x * 4 + wave;
    const int ty   = t >> 9;
    const int tx   = t & 511;

    float acc = 0.0f;
    float w   = 0.0f;

#pragma unroll
    for (int dy = -1; dy <= 1; ++dy) {
#pragma unroll
        for (int dx = -1; dx <= 1; ++dx) {
            const int sy = ty - dy, sx = tx - dx;
            if (sy < 0 || sy >= HS || sx < 0 || sx >= WSZ) continue;
            const int sidx = sy * WSZ + sx;

            // ---- pass 1 (source -> reference), pure gather ----
            {
                const int2 nn = nnf_sr[sidx];        // (ry, rx)
                const int qy = nn.x + dy, qx = nn.y + dx;
                if (qy >= 0 && qy < HS && qx >= 0 && qx < WSZ) {
                    const int q = qy * WSZ + qx;
                    const float v = TRANSPOSED
                        ? refp[(size_t)q * NC + lane]
                        : refp[(size_t)lane * HW + q];
                    acc += v * ws;
                    w   += ws;
                }
            }

            // ---- pass 2 (reference -> source), via inverted lists ----
            int r = head[sidx];
            while (r >= 0) {
                const int ry = r >> 9, rx = r & 511;
                const int qy = ry + dy, qx = rx + dx;
                if (qy >= 0 && qy < HS && qx >= 0 && qx < WSZ) {
                    const int q = qy * WSZ + qx;
                    const float v = TRANSPOSED
                        ? refp[(size_t)q * NC + lane]
                        : refp[(size_t)lane * HW + q];
                    acc += v * wr;
                    w   += wr;
                }
                r = nextp[r];
            }
        }
    }

    if (w == 0.0f) w = 1.0f;
    out[(size_t)lane * HW + t] = acc / w;
}

extern "C" void kernel_launch(void* const* d_in, const int* in_sizes, int n_in,
                              void* d_out, int out_size, void* d_ws, size_t ws_size,
                              hipStream_t stream)
{
    const float* ref    = (const float*)d_in[0];
    const int2*  nnf_sr = (const int2*)d_in[1];
    const int2*  nnf_rs = (const int2*)d_in[2];
    float* out = (float*)d_out;

    char* wsb = (char*)d_ws;
    const size_t refT_bytes = (size_t)HW * NC * sizeof(float);   // 64 MiB
    const size_t list_bytes = (size_t)HW * sizeof(int);          // 1 MiB each

    if (ws_size >= refT_bytes + 2 * list_bytes) {
        float* refT  = (float*)wsb;
        int*   head  = (int*)(wsb + refT_bytes);
        int*   nextp = head + HW;

        hipMemsetAsync(head, 0xFF, list_bytes, stream);          // head = -1
        transpose_kernel<<<HW / 64, 256, 0, stream>>>(ref, refT);
        fill_kernel<<<HW / 256, 256, 0, stream>>>(nnf_rs, head, nextp);
        gather_kernel<true><<<HW / 4, 256, 0, stream>>>(refT, nnf_sr, head, nextp, out);
    } else {
        // fallback: no room for transposed ref; gather channel-major directly
        int* head  = (int*)wsb;
        int* nextp = head + HW;
        hipMemsetAsync(head, 0xFF, list_bytes, stream);
        fill_kernel<<<HW / 256, 256, 0, stream>>>(nnf_rs, head, nextp);
        gather_kernel<false><<<HW / 4, 256, 0, stream>>>(ref, nnf_sr, head, nextp, out);
    }
}

// Round 2
// 407.904 us; speedup vs baseline: 1.6013x; 1.6013x over previous
//
#include <hip/hip_runtime.h>

#define HS   512
#define WSZ  512
#define NC   64
#define HW   (HS * WSZ)
#define KCAP 16

typedef unsigned int uint;
typedef unsigned short ushort;

// float -> bf16 (round-to-nearest-even), returned as raw bits
__device__ __forceinline__ ushort f2bf(float f) {
    uint b = __float_as_uint(f);
    uint r = (b + 0x7FFFu + ((b >> 16) & 1u)) >> 16;
    return (ushort)r;
}

// ---------------------------------------------------------------------------
// Transpose ref (C,H,W) f32 -> refu (H*W, 32) uint, each uint = packed bf16
// pair (channels 2c, 2c+1).  64-pixel tile per block via padded LDS.
// ---------------------------------------------------------------------------
__global__ __launch_bounds__(256) void transpose_bf16(
    const float* __restrict__ ref, uint* __restrict__ refu)
{
    __shared__ float lds[64 * 65];
    const int p0  = blockIdx.x * 64;
    const int tid = threadIdx.x;
#pragma unroll
    for (int k = 0; k < 16; ++k) {
        int e = k * 256 + tid;
        int c = e >> 6;            // channel
        int i = e & 63;            // pixel in tile
        lds[i * 65 + c] = ref[(size_t)c * HW + p0 + i];   // 256B coalesced
    }
    __syncthreads();
#pragma unroll
    for (int k = 0; k < 8; ++k) {
        int e  = k * 256 + tid;    // 2048 uints per tile
        int i  = e >> 5;
        int cp = e & 31;           // channel pair
        ushort lo = f2bf(lds[i * 65 + 2 * cp]);
        ushort hi = f2bf(lds[i * 65 + 2 * cp + 1]);
        refu[(size_t)(p0 + i) * 32 + cp] = (uint)lo | ((uint)hi << 16);
    }
}

// ---------------------------------------------------------------------------
// Invert nnf_rs into fixed-capacity bins: bin = nnf_rs[r] (target center).
// Poisson(1) per bin; KCAP=16 overflow prob ~1e-14 per bin.
// ---------------------------------------------------------------------------
__global__ __launch_bounds__(256) void fill_bins(
    const int2* __restrict__ nnf_rs, int* __restrict__ cnt,
    int* __restrict__ slots)
{
    int r = blockIdx.x * 256 + threadIdx.x;
    int2 s = nnf_rs[r];                    // (sy, sx)
    int bin = (s.x << 9) | s.y;            // values guaranteed in [0,512)
    int pos = atomicAdd(&cnt[bin], 1);
    if (pos < KCAP) slots[(bin << 4) + pos] = r;
}

// ---------------------------------------------------------------------------
// Gather: one wave = 2 targets (one per half-wave). Lane l32 owns channel
// pair (2*l32, 2*l32+1) read as one packed uint (PACKED) or two f32 from
// channel-major ref (fallback).  All loads are predicated (no divergent
// continue), addresses computable -> max 3 dependency levels.
// ---------------------------------------------------------------------------
template <bool PACKED>
__global__ __launch_bounds__(256) void gather2(
    const uint*  __restrict__ refu,
    const float* __restrict__ reff,
    const int2*  __restrict__ nnf_sr,
    const int*   __restrict__ cnt,
    const int*   __restrict__ slots,
    float* __restrict__ out)
{
    const float ws = 1.0f / 262144.0f;     // 2^-18, exact
    const float wr = 2.0f / 262144.0f;     // 2^-17, exact

    const int lane = threadIdx.x & 63;
    const int wv   = threadIdx.x >> 6;
    const int half = lane >> 5;
    const int l32  = lane & 31;
    const int t    = blockIdx.x * 8 + wv * 2 + half;
    const int ty   = t >> 9;
    const int tx   = t & 511;

    float a0 = 0.f, a1 = 0.f, w = 0.f;
    int bins[9];
    int cnts[9];

    // ---- pass 1 (src->ref gather) + bin metadata prefetch, fully unrolled ----
#pragma unroll
    for (int i = 0; i < 9; ++i) {
        const int dy = i / 3 - 1, dx = i % 3 - 1;
        const int sy = ty - dy, sx = tx - dx;
        const bool sval = ((unsigned)sy < 512u) & ((unsigned)sx < 512u);
        const int sidx = ((sy & 511) << 9) | (sx & 511);
        bins[i] = sidx;
        const int2 nn = nnf_sr[sidx];
        const int c   = cnt[sidx];
        cnts[i] = sval ? min(c, KCAP) : 0;
        const int qy = nn.x + dy, qx = nn.y + dx;
        const bool v = sval & ((unsigned)qy < 512u) & ((unsigned)qx < 512u);
        const int q  = ((qy & 511) << 9) | (qx & 511);
        const float m = v ? ws : 0.f;
        float f0, f1;
        if (PACKED) {
            uint u = refu[((size_t)q << 5) + l32];
            f0 = __uint_as_float(u << 16);
            f1 = __uint_as_float(u & 0xffff0000u);
        } else {
            f0 = reff[(size_t)(2 * l32) * HW + q];
            f1 = reff[(size_t)(2 * l32 + 1) * HW + q];
        }
        a0 += f0 * m;
        a1 += f1 * m;
        w  += m;
    }

    // ---- pass 2 (ref->src via inverted bins), lockstep over slot level j ----
    int mc = 0;
#pragma unroll
    for (int i = 0; i < 9; ++i) mc = max(mc, cnts[i]);
    mc = max(mc, __shfl_xor(mc, 32));      // wave max across both halves

    for (int j = 0; j < mc; ++j) {
#pragma unroll
        for (int i = 0; i < 9; ++i) {
            if (__any(j < cnts[i])) {
                const int dy = i / 3 - 1, dx = i % 3 - 1;
                const int jj = min(j, max(cnts[i] - 1, 0));
                const int e  = slots[(bins[i] << 4) + jj];
                const int ry = (e >> 9) & 511, rx = e & 511;
                const int qy = ry + dy, qx = rx + dx;
                const bool v = (j < cnts[i]) &
                               ((unsigned)qy < 512u) & ((unsigned)qx < 512u);
                const int q  = ((qy & 511) << 9) | (qx & 511);
                const float m = v ? wr : 0.f;
                float f0, f1;
                if (PACKED) {
                    uint u = refu[((size_t)q << 5) + l32];
                    f0 = __uint_as_float(u << 16);
                    f1 = __uint_as_float(u & 0xffff0000u);
                } else {
                    f0 = reff[(size_t)(2 * l32) * HW + q];
                    f1 = reff[(size_t)(2 * l32 + 1) * HW + q];
                }
                a0 += f0 * m;
                a1 += f1 * m;
                w  += m;
            }
        }
    }

    if (w == 0.f) w = 1.f;
    const float inv = 1.f / w;
    out[(size_t)(2 * l32) * HW + t]     = a0 * inv;
    out[(size_t)(2 * l32 + 1) * HW + t] = a1 * inv;
}

extern "C" void kernel_launch(void* const* d_in, const int* in_sizes, int n_in,
                              void* d_out, int out_size, void* d_ws, size_t ws_size,
                              hipStream_t stream)
{
    const float* ref    = (const float*)d_in[0];
    const int2*  nnf_sr = (const int2*)d_in[1];
    const int2*  nnf_rs = (const int2*)d_in[2];
    float* out = (float*)d_out;

    char* wsb = (char*)d_ws;
    const size_t refT_bytes = (size_t)HW * NC * 2;        // 32 MiB packed bf16
    const size_t cnt_bytes  = (size_t)HW * 4;             //  1 MiB
    const size_t slot_bytes = (size_t)HW * KCAP * 4;      // 16 MiB

    if (ws_size >= refT_bytes + cnt_bytes + slot_bytes) {
        uint* refu  = (uint*)wsb;
        int*  cntp  = (int*)(wsb + refT_bytes);
        int*  slots = (int*)(wsb + refT_bytes + cnt_bytes);

        hipMemsetAsync(cntp, 0, cnt_bytes, stream);
        transpose_bf16<<<HW / 64, 256, 0, stream>>>(ref, refu);
        fill_bins<<<HW / 256, 256, 0, stream>>>(nnf_rs, cntp, slots);
        gather2<true><<<HW / 8, 256, 0, stream>>>(refu, nullptr, nnf_sr,
                                                  cntp, slots, out);
    } else {
        // fallback: bins only, gather from channel-major f32 ref directly
        int* cntp  = (int*)wsb;
        int* slots = cntp + HW;
        hipMemsetAsync(cntp, 0, cnt_bytes, stream);
        fill_bins<<<HW / 256, 256, 0, stream>>>(nnf_rs, cntp, slots);
        gather2<false><<<HW / 8, 256, 0, stream>>>(nullptr, ref, nnf_sr,
                                                   cntp, slots, out);
    }
}

// Round 3
// 266.796 us; speedup vs baseline: 2.4482x; 1.5289x over previous
//
#include <hip/hip_runtime.h>

#define HS   512
#define WSZ  512
#define NC   64
#define HW   (HS * WSZ)
#define KCAP 16

typedef unsigned int uint;
typedef unsigned short ushort;

// float -> bf16 (round-to-nearest-even), raw bits
__device__ __forceinline__ ushort f2bf(float f) {
    uint b = __float_as_uint(f);
    return (ushort)((b + 0x7FFFu + ((b >> 16) & 1u)) >> 16);
}

// ---------------------------------------------------------------------------
// prep: transpose ref (C,H,W) f32 -> refu (H*W, 32) packed bf16 pairs,
// and zero the bin counters (folds the old memset dispatch in).
// ---------------------------------------------------------------------------
__global__ __launch_bounds__(256) void prep_kernel(
    const float* __restrict__ ref, uint* __restrict__ refu,
    int* __restrict__ cnt)
{
    __shared__ float lds[64 * 65];
    const int p0  = blockIdx.x * 64;
    const int tid = threadIdx.x;
    if (tid < 64) cnt[blockIdx.x * 64 + tid] = 0;   // 4096*64 == HW
#pragma unroll
    for (int k = 0; k < 16; ++k) {
        int e = k * 256 + tid;
        int c = e >> 6, i = e & 63;
        lds[i * 65 + c] = ref[(size_t)c * HW + p0 + i];   // coalesced
    }
    __syncthreads();
#pragma unroll
    for (int k = 0; k < 8; ++k) {
        int e  = k * 256 + tid;
        int i  = e >> 5, cp = e & 31;
        ushort lo = f2bf(lds[i * 65 + 2 * cp]);
        ushort hi = f2bf(lds[i * 65 + 2 * cp + 1]);
        refu[(size_t)(p0 + i) * 32 + cp] = (uint)lo | ((uint)hi << 16);
    }
}

// ---------------------------------------------------------------------------
// Invert nnf_rs into fixed-capacity bins (bin = nnf_rs value, the scatter
// target center). Poisson(1)/bin; P(count>16) ~ 1e-14.
// ---------------------------------------------------------------------------
__global__ __launch_bounds__(256) void fill_bins(
    const int2* __restrict__ nnf_rs, int* __restrict__ cnt,
    int* __restrict__ slots)
{
    int r = blockIdx.x * 256 + threadIdx.x;
    int2 s = nnf_rs[r];                 // (sy, sx), values in [0,512)
    int bin = (s.x << 9) | s.y;
    int pos = atomicAdd(&cnt[bin], 1);
    if (pos < KCAP) slots[(bin << 4) + pos] = r;
}

// ---------------------------------------------------------------------------
// Gather: 8 targets/wave, 8 lanes/target, lane covers 8 channels via one
// uint4 (16B) load -> one address calc feeds 128B/group.  Pass 2 walks a
// register-compacted entry list (prefix sums over the 9 bins + cndmask-chain
// bin select): no ballots, no lockstep waste.
// ---------------------------------------------------------------------------
template <bool PACKED>
__global__ __launch_bounds__(256, 6) void gather8(
    const uint4* __restrict__ refu4,
    const float* __restrict__ reff,
    const int2*  __restrict__ nnf_sr,
    const int*   __restrict__ cnt,
    const int*   __restrict__ slots,
    float* __restrict__ out)
{
    const float ws = 1.0f / 262144.0f;   // 2^-18 exact
    const float wr = 2.0f / 262144.0f;   // 2^-17 exact

    const int tid = threadIdx.x;
    const int k   = tid & 7;                       // channel-quad (8 ch)
    const int t   = blockIdx.x * 32 + (tid >> 3);  // 32 targets / block
    const int ty  = t >> 9, tx = t & 511;

    float a0=0,a1=0,a2=0,a3=0,a4=0,a5=0,a6=0,a7=0, w=0.f;

    auto accum = [&](int q, float m) {
        if (PACKED) {
            uint4 u = refu4[(size_t)q * 8 + k];
            a0 += __uint_as_float(u.x << 16)         * m;
            a1 += __uint_as_float(u.x & 0xffff0000u) * m;
            a2 += __uint_as_float(u.y << 16)         * m;
            a3 += __uint_as_float(u.y & 0xffff0000u) * m;
            a4 += __uint_as_float(u.z << 16)         * m;
            a5 += __uint_as_float(u.z & 0xffff0000u) * m;
            a6 += __uint_as_float(u.w << 16)         * m;
            a7 += __uint_as_float(u.w & 0xffff0000u) * m;
        } else {
            const size_t c0 = (size_t)(8 * k) * HW + q;
            a0 += reff[c0 + 0*(size_t)HW] * m;  a1 += reff[c0 + 1*(size_t)HW] * m;
            a2 += reff[c0 + 2*(size_t)HW] * m;  a3 += reff[c0 + 3*(size_t)HW] * m;
            a4 += reff[c0 + 4*(size_t)HW] * m;  a5 += reff[c0 + 5*(size_t)HW] * m;
            a6 += reff[c0 + 6*(size_t)HW] * m;  a7 += reff[c0 + 7*(size_t)HW] * m;
        }
        w += m;
    };

    int cbase[9];   // slots base per neighbor bin
    int pfx[9];     // entry-list start offset per bin
    int run = 0;

    // ---- pass 1 (src->ref gather) + bin metadata / prefix sums ----
#pragma unroll
    for (int i = 0; i < 9; ++i) {
        const int dy = i / 3 - 1, dx = i % 3 - 1;
        const int sy = ty - dy, sx = tx - dx;
        const bool sval = ((unsigned)sy < 512u) & ((unsigned)sx < 512u);
        const int sidx = ((sy & 511) << 9) | (sx & 511);
        cbase[i] = sidx << 4;
        pfx[i]   = run;
        int c = cnt[sidx];
        run += sval ? min(c, KCAP) : 0;
        const int2 nn = nnf_sr[sidx];
        const int qy = nn.x + dy, qx = nn.y + dx;
        const bool v = sval & ((unsigned)qy < 512u) & ((unsigned)qx < 512u);
        const int q  = ((qy & 511) << 9) | (qx & 511);
        accum(q, v ? ws : 0.f);
    }
    const int S = run;

    // ---- pass 2: compacted entry walk, branch-free bin select ----
    auto entry = [&](int s) {
        int b = cbase[0], off = 0, ii = 0;
#pragma unroll
        for (int i = 1; i < 9; ++i) {
            const bool c = (s >= pfx[i]);
            b   = c ? cbase[i] : b;
            off = c ? pfx[i]   : off;
            ii  = c ? i        : ii;
        }
        const int idx = min(s - off, KCAP - 1);     // clamp keeps addr in-bounds
        const int e   = slots[b + idx];
        const int ry  = (e >> 9) & 511, rx = e & 511;
        const int dy  = ((ii * 11) >> 5) - 1;       // ii/3 - 1
        const int dx  = ii - 3 * (dy + 1) - 1;      // ii%3 - 1
        const int qy  = ry + dy, qx = rx + dx;
        const bool v  = (s < S) & ((unsigned)qy < 512u) & ((unsigned)qx < 512u);
        const int q   = ((qy & 511) << 9) | (qx & 511);
        accum(q, v ? wr : 0.f);
    };

    for (int s = 0; s < S; s += 2) {   // unroll x2 for MLP
        entry(s);
        entry(s + 1);
    }

    // ---- epilogue ----
    if (w == 0.f) w = 1.f;             // unreachable (center tap always valid)
    const float inv = 1.f / w;
    size_t o = (size_t)(8 * k) * HW + t;
    out[o]              = a0 * inv;
    out[o + 1*(size_t)HW] = a1 * inv;
    out[o + 2*(size_t)HW] = a2 * inv;
    out[o + 3*(size_t)HW] = a3 * inv;
    out[o + 4*(size_t)HW] = a4 * inv;
    out[o + 5*(size_t)HW] = a5 * inv;
    out[o + 6*(size_t)HW] = a6 * inv;
    out[o + 7*(size_t)HW] = a7 * inv;
}

extern "C" void kernel_launch(void* const* d_in, const int* in_sizes, int n_in,
                              void* d_out, int out_size, void* d_ws, size_t ws_size,
                              hipStream_t stream)
{
    const float* ref    = (const float*)d_in[0];
    const int2*  nnf_sr = (const int2*)d_in[1];
    const int2*  nnf_rs = (const int2*)d_in[2];
    float* out = (float*)d_out;

    char* wsb = (char*)d_ws;
    const size_t refT_bytes = (size_t)HW * NC * 2;        // 32 MiB packed bf16
    const size_t cnt_bytes  = (size_t)HW * 4;             //  1 MiB
    const size_t slot_bytes = (size_t)HW * KCAP * 4;      // 16 MiB

    if (ws_size >= refT_bytes + cnt_bytes + slot_bytes) {
        uint* refu  = (uint*)wsb;
        int*  cntp  = (int*)(wsb + refT_bytes);
        int*  slots = (int*)(wsb + refT_bytes + cnt_bytes);

        prep_kernel<<<HW / 64, 256, 0, stream>>>(ref, refu, cntp);
        fill_bins<<<HW / 256, 256, 0, stream>>>(nnf_rs, cntp, slots);
        gather8<true><<<HW / 32, 256, 0, stream>>>((const uint4*)refu, nullptr,
                                                   nnf_sr, cntp, slots, out);
    } else {
        // fallback: bins only, gather channel-major f32 ref directly
        int* cntp  = (int*)wsb;
        int* slots = cntp + HW;
        hipMemsetAsync(cntp, 0, cnt_bytes, stream);
        fill_bins<<<HW / 256, 256, 0, stream>>>(nnf_rs, cntp, slots);
        gather8<false><<<HW / 32, 256, 0, stream>>>(nullptr, ref, nnf_sr,
                                                    cntp, slots, out);
    }
}